// Round 9
// baseline (1125.436 us; speedup 1.0000x reference)
//
#include <hip/hip_runtime.h>
#include <hip/hip_fp16.h>

#define IN_F   2048
#define OUT_F  2048
#define NNZ_   1048576
#define BATCH  8192
#define W_ROW0 6144
#define W_BASE ((size_t)W_ROW0 * OUT_F)   // W fp32 parked at out rows [6144,8192)

__device__ __forceinline__ float bfval(unsigned short b) {
    union { unsigned int u; float f; } t; t.u = ((unsigned int)b) << 16; return t.f;
}
__device__ __forceinline__ unsigned short f2bf(float f) {
    union { float f; unsigned int u; } v; v.f = f;
    unsigned int u = v.u; u += 0x7FFF + ((u >> 16) & 1);   // RNE
    return (unsigned short)(u >> 16);
}
__device__ __forceinline__ float h2f(unsigned short b) {
    union { unsigned short u; __half h; } t; t.u = b; return __half2float(t.h);
}

// ---- zero the W region (replay-idempotent: runs every call) ----
__global__ void zero_f32_kernel(float4* __restrict__ p, int n4) {
    int s = gridDim.x * blockDim.x;
    for (int i = blockIdx.x * blockDim.x + threadIdx.x; i < n4; i += s)
        p[i] = float4{0.f, 0.f, 0.f, 0.f};
}

// ---- scatter COO -> dense W, 3-way weights-dtype detection ----
// windows on first 512 u16 samples (256 floats if fp32-delivered):
//   bf16 bits:  bf16-interp max ~0.06   in (1e-3,16);   fp16 window then irrelevant
//   fp16 bits:  bf16-interp max ~5e-11  (fails);  fp16-interp max ~0.06 in window
//   fp32 vals:  both u16 interps see random-exponent garbage >16 -> read as float
__global__ void scatter_w_kernel(const unsigned short* __restrict__ wbits,
                                 const int* __restrict__ coords,
                                 float* __restrict__ W, int nnz) {
    __shared__ unsigned int sbf, sfh;
    if (threadIdx.x == 0) { sbf = 0u; sfh = 0u; }
    __syncthreads();
    unsigned int mbf = 0u, mfh = 0u;
    for (int i = threadIdx.x; i < 512; i += blockDim.x) {
        unsigned short b = wbits[i];
        unsigned int abf = (((unsigned int)b) << 16) & 0x7FFFFFFFu;  // |bf16| bits
        unsigned int afh = (unsigned int)(b & 0x7FFF);               // |fp16| bits
        mbf = mbf > abf ? mbf : abf;
        mfh = mfh > afh ? mfh : afh;
    }
    atomicMax(&sbf, mbf); atomicMax(&sfh, mfh);
    __syncthreads();
    union { unsigned int u; float f; } tb; tb.u = sbf;
    float bmax = tb.f;
    float hmax = h2f((unsigned short)sfh);
    int mode = (bmax > 1e-3f && bmax < 16.f) ? 0
             : (hmax > 1e-3f && hmax < 16.f) ? 1 : 2;

    int i = blockIdx.x * blockDim.x + threadIdx.x;
    if (i < nnz) {
        float v;
        if (mode == 0)      v = bfval(wbits[i]);
        else if (mode == 1) v = h2f(wbits[i]);
        else                v = ((const float*)wbits)[i];
        atomicAdd(&W[coords[i] & (OUT_F * IN_F - 1)], v);   // mask: OOB impossible
    }
}

// ---- W fp32 -> wb bf16 (ws-resident; W dead afterwards) ----
__global__ void f32_to_bf16_kernel(const float4* __restrict__ in,
                                   ushort4* __restrict__ out, int n4) {
    int s = gridDim.x * blockDim.x;
    for (int i = blockIdx.x * blockDim.x + threadIdx.x; i < n4; i += s) {
        float4 v = in[i];
        ushort4 o;
        o.x = f2bf(v.x); o.y = f2bf(v.y); o.z = f2bf(v.z); o.w = f2bf(v.w);
        out[i] = o;
    }
}

// ---- pure-VALU fp32 SGEMM: out[8192][2048] = x * wb^T, 64x64 tiles ----
// No MFMA, no fragment layouts. Reads only x and wb; writes all of out.
__global__ __launch_bounds__(256) void sgemm_kernel(
    const float* __restrict__ x,              // [BATCH][IN_F] fp32
    const unsigned short* __restrict__ wb,    // [OUT_F][IN_F] bf16 bits
    float* __restrict__ out) {                // [BATCH][OUT_F] fp32
    constexpr int LD = 36;                    // 144B rows: 16B-aligned, 2-way alias
    __shared__ __align__(16) float xs[64 * LD];
    __shared__ __align__(16) float bs[64 * LD];
    const int tid  = threadIdx.x;
    const int tx   = tid & 15, ty = tid >> 4;
    const int brow = blockIdx.y * 64, bcol = blockIdx.x * 64;
    const int srow = tid >> 2, sc4 = (tid & 3) * 4;   // stage map: 64 rows x 16 cols

    float acc[4][4] = {};   // rows ty*4+i, cols j*16+tx

    for (int kt = 0; kt < IN_F / 16; ++kt) {
        float4  xv = *(const float4*) &x [(size_t)(brow + srow) * IN_F + kt * 16 + sc4];
        ushort4 wv = *(const ushort4*)&wb[(size_t)(bcol + srow) * IN_F + kt * 16 + sc4];
        __syncthreads();                       // prior iter's LDS reads complete
        *(float4*)&xs[srow * LD + sc4] = xv;
        float4 bv;
        bv.x = bfval(wv.x); bv.y = bfval(wv.y);
        bv.z = bfval(wv.z); bv.w = bfval(wv.w);
        *(float4*)&bs[srow * LD + sc4] = bv;
        __syncthreads();
#pragma unroll
        for (int k0 = 0; k0 < 16; k0 += 4) {
            float4 a4[4], b4[4];
#pragma unroll
            for (int i = 0; i < 4; ++i)        // broadcast across tx: conflict-free
                a4[i] = *(const float4*)&xs[(ty * 4 + i) * LD + k0];
#pragma unroll
            for (int j = 0; j < 4; ++j)        // lane stride LD=36: 2-way, free
                b4[j] = *(const float4*)&bs[(j * 16 + tx) * LD + k0];
#pragma unroll
            for (int i = 0; i < 4; ++i)
#pragma unroll
                for (int j = 0; j < 4; ++j)
                    acc[i][j] += a4[i].x * b4[j].x + a4[i].y * b4[j].y
                               + a4[i].z * b4[j].z + a4[i].w * b4[j].w;
        }
    }
#pragma unroll
    for (int i = 0; i < 4; ++i)
#pragma unroll
        for (int j = 0; j < 4; ++j)
            out[(size_t)(brow + ty * 4 + i) * OUT_F + bcol + j * 16 + tx]
                = acc[i][j];
}

extern "C" void kernel_launch(void* const* d_in, const int* in_sizes, int n_in,
                              void* d_out, int out_size, void* d_ws, size_t ws_size,
                              hipStream_t stream) {
    const float*          x      = (const float*)d_in[0];
    const unsigned short* wbits  = (const unsigned short*)d_in[1];
    const int*            coords = (const int*)d_in[2];   // int32 (r1->r2 crash bisect)
    float*                out    = (float*)d_out;         // fp32 (r8 stash decode)

    // W fp32 (16 MiB) parked in out rows [6144,8192); dead after conversion,
    // so the SGEMM's in-place writes of all 8192 rows are hazard-free.
    float*          W  = out + W_BASE;
    // wb bf16 (8 MiB) in ws (r8: ws_size >= 9 MiB).
    unsigned short* wb = (unsigned short*)d_ws;
    (void)ws_size;

    zero_f32_kernel<<<512, 256, 0, stream>>>((float4*)W, OUT_F * IN_F / 4);
    scatter_w_kernel<<<NNZ_ / 256, 256, 0, stream>>>(wbits, coords, W, NNZ_);
    f32_to_bf16_kernel<<<1024, 256, 0, stream>>>(
        (const float4*)W, (ushort4*)wb, OUT_F * IN_F / 4);

    dim3 grid(OUT_F / 64, BATCH / 64);   // 32 x 128
    sgemm_kernel<<<grid, 256, 0, stream>>>(x, wb, out);
}

// Round 10
// 195.615 us; speedup vs baseline: 5.7533x; 5.7533x over previous
//
#include <hip/hip_runtime.h>
#include <hip/hip_fp16.h>

#define IN_F   2048
#define OUT_F  2048
#define NNZ_   1048576
#define BATCH  8192
#define W_ROW0 6144
#define W_BASE ((size_t)W_ROW0 * OUT_F)   // W fp32 parked at out rows [6144,8192)

typedef __bf16 bf16x8 __attribute__((ext_vector_type(8)));
typedef float  f32x4  __attribute__((ext_vector_type(4)));

__device__ __forceinline__ float bfval(unsigned short b) {
    union { unsigned int u; float f; } t; t.u = ((unsigned int)b) << 16; return t.f;
}
__device__ __forceinline__ unsigned short f2bf(float f) {
    union { float f; unsigned int u; } v; v.f = f;
    unsigned int u = v.u; u += 0x7FFF + ((u >> 16) & 1);   // RNE
    return (unsigned short)(u >> 16);
}
__device__ __forceinline__ float h2f(unsigned short b) {
    union { unsigned short u; __half h; } t; t.u = b; return __half2float(t.h);
}

// async global->LDS, 16B/lane; LDS dest = wave-uniform base + lane*16
__device__ __forceinline__ void gload_lds16(const void* g, void* l) {
    __builtin_amdgcn_global_load_lds(
        (const __attribute__((address_space(1))) unsigned int*)g,
        (__attribute__((address_space(3))) unsigned int*)l,
        16, 0, 0);
}

// ---- zero the W region (replay-idempotent) ----
__global__ void zero_f32_kernel(float4* __restrict__ p, int n4) {
    int s = gridDim.x * blockDim.x;
    for (int i = blockIdx.x * blockDim.x + threadIdx.x; i < n4; i += s)
        p[i] = float4{0.f, 0.f, 0.f, 0.f};
}

// ---- scatter COO -> dense W, 3-way dtype detection (r9-proven verbatim) ----
__global__ void scatter_w_kernel(const unsigned short* __restrict__ wbits,
                                 const int* __restrict__ coords,
                                 float* __restrict__ W, int nnz) {
    __shared__ unsigned int sbf, sfh;
    if (threadIdx.x == 0) { sbf = 0u; sfh = 0u; }
    __syncthreads();
    unsigned int mbf = 0u, mfh = 0u;
    for (int i = threadIdx.x; i < 512; i += blockDim.x) {
        unsigned short b = wbits[i];
        unsigned int abf = (((unsigned int)b) << 16) & 0x7FFFFFFFu;
        unsigned int afh = (unsigned int)(b & 0x7FFF);
        mbf = mbf > abf ? mbf : abf;
        mfh = mfh > afh ? mfh : afh;
    }
    atomicMax(&sbf, mbf); atomicMax(&sfh, mfh);
    __syncthreads();
    union { unsigned int u; float f; } tb; tb.u = sbf;
    float bmax = tb.f;
    float hmax = h2f((unsigned short)sfh);
    int mode = (bmax > 1e-3f && bmax < 16.f) ? 0
             : (hmax > 1e-3f && hmax < 16.f) ? 1 : 2;   // r9 resolved: mode 2 (fp32)

    int i = blockIdx.x * blockDim.x + threadIdx.x;
    if (i < nnz) {
        float v;
        if (mode == 0)      v = bfval(wbits[i]);
        else if (mode == 1) v = h2f(wbits[i]);
        else                v = ((const float*)wbits)[i];
        atomicAdd(&W[coords[i] & (OUT_F * IN_F - 1)], v);
    }
}

// ---- fp32 -> bf16, vectorized ----
__global__ void f32_to_bf16_kernel(const float4* __restrict__ in,
                                   ushort4* __restrict__ out, int n4) {
    int s = gridDim.x * blockDim.x;
    for (int i = blockIdx.x * blockDim.x + threadIdx.x; i < n4; i += s) {
        float4 v = in[i];
        ushort4 o;
        o.x = f2bf(v.x); o.y = f2bf(v.y); o.z = f2bf(v.z); o.w = f2bf(v.w);
        out[i] = o;
    }
}

// ---- main GEMM: m97 structure, both operands bf16, gload_lds staging ----
// out[M][N](fp32) = xb[M][K] * wb[N][K]^T    (r3-validated structure)
__global__ __launch_bounds__(256) void gemm_bf16_kernel(
    const unsigned short* __restrict__ xb,
    const unsigned short* __restrict__ wb,
    float* __restrict__ out) {
    constexpr int K = IN_F, N = OUT_F;
    constexpr int BM = 128, BN = 128, BK = 32;

    __shared__ __align__(16) unsigned short As[BM * BK];   // 8 KB
    __shared__ __align__(16) unsigned short Bs[BN * BK];   // 8 KB

    const int tid  = threadIdx.x;
    const int lane = tid & 63;
    const int wave = tid >> 6;
    const int wr   = wave >> 1;
    const int wc   = wave & 1;
    const int brow = blockIdx.y * BM;
    const int bcol = blockIdx.x * BN;

    f32x4 acc[4][4] = {};

    const int ldrow  = tid >> 2;
    const int ldkb   = (tid & 3) * 16;
    const int ldsoff = wave * 512;

    const int frow = lane & 15;
    const int koff = (lane >> 4) * 8;

    for (int kt = 0; kt < K / BK; ++kt) {
        const size_t kbyte = (size_t)kt * BK * 2;
#pragma unroll
        for (int c = 0; c < 2; ++c) {
            const char* g = (const char*)xb
                + ((size_t)(brow + c * 64 + ldrow) * K) * 2 + kbyte + ldkb;
            gload_lds16(g, &As[c * 2048 + ldsoff]);
        }
#pragma unroll
        for (int c = 0; c < 2; ++c) {
            const char* g = (const char*)wb
                + ((size_t)(bcol + c * 64 + ldrow) * K) * 2 + kbyte + ldkb;
            gload_lds16(g, &Bs[c * 2048 + ldsoff]);
        }
        __syncthreads();

        bf16x8 a[4], b[4];
#pragma unroll
        for (int m = 0; m < 4; ++m)
            a[m] = *(const bf16x8*)&As[(wr * 64 + m * 16 + frow) * BK + koff];
#pragma unroll
        for (int n = 0; n < 4; ++n)
            b[n] = *(const bf16x8*)&Bs[(wc * 64 + n * 16 + frow) * BK + koff];
#pragma unroll
        for (int m = 0; m < 4; ++m)
#pragma unroll
            for (int n = 0; n < 4; ++n)
                acc[m][n] = __builtin_amdgcn_mfma_f32_16x16x32_bf16(
                    a[m], b[n], acc[m][n], 0, 0, 0);
        __syncthreads();
    }

    const int orow0 = brow + wr * 64 + (lane >> 4) * 4;
    const int ocol0 = bcol + wc * 64 + (lane & 15);
#pragma unroll
    for (int m = 0; m < 4; ++m)
#pragma unroll
        for (int n = 0; n < 4; ++n)
#pragma unroll
            for (int r = 0; r < 4; ++r)
                out[(size_t)(orow0 + m * 16 + r) * N + (ocol0 + n * 16)]
                    = acc[m][n][r];
}

// ---- fallback GEMM (ws too small for xb): A = fp32 x, inline cvt (r5 core) ----
__global__ __launch_bounds__(256) void gemm_a32_kernel(
    const float* __restrict__ x,
    const unsigned short* __restrict__ wb,
    float* __restrict__ out) {
    constexpr int K = IN_F, N = OUT_F;
    constexpr int BM = 128, BN = 128, BK = 32, LDA = 36;

    __shared__ __align__(16) float Af[BM * LDA];
    __shared__ __align__(16) unsigned short Bs[BN * BK];

    const int tid  = threadIdx.x;
    const int lane = tid & 63;
    const int wave = tid >> 6;
    const int wr   = wave >> 1;
    const int wc   = wave & 1;
    const int brow = blockIdx.y * BM;
    const int bcol = blockIdx.x * BN;

    f32x4 acc[4][4] = {};

    const int arow = tid >> 3;
    const int acol = (tid & 7) * 4;
    const int brow_ld = tid >> 2;
    const int bk_ld   = (tid & 3) * 8;
    const int frow = lane & 15;
    const int koff = (lane >> 4) * 8;

    for (int kt = 0; kt < K / BK; ++kt) {
        uint4 bv[2];
#pragma unroll
        for (int c = 0; c < 2; ++c)
            bv[c] = *(const uint4*)&wb[(size_t)(bcol + c * 64 + brow_ld) * K
                                       + kt * BK + bk_ld];
        float4 av[4];
#pragma unroll
        for (int c = 0; c < 4; ++c)
            av[c] = *(const float4*)&x[(size_t)(brow + c * 32 + arow) * K
                                       + kt * BK + acol];
#pragma unroll
        for (int c = 0; c < 2; ++c)
            *(uint4*)&Bs[(c * 64 + brow_ld) * BK + bk_ld] = bv[c];
#pragma unroll
        for (int c = 0; c < 4; ++c)
            *(float4*)&Af[(c * 32 + arow) * LDA + acol] = av[c];
        __syncthreads();

        bf16x8 a[4], b[4];
#pragma unroll
        for (int m = 0; m < 4; ++m) {
            const float* ap = &Af[(wr * 64 + m * 16 + frow) * LDA + koff];
            f32x4 lo = *(const f32x4*)ap, hi = *(const f32x4*)(ap + 4);
            bf16x8 t;
            t[0] = (__bf16)lo[0]; t[1] = (__bf16)lo[1];
            t[2] = (__bf16)lo[2]; t[3] = (__bf16)lo[3];
            t[4] = (__bf16)hi[0]; t[5] = (__bf16)hi[1];
            t[6] = (__bf16)hi[2]; t[7] = (__bf16)hi[3];
            a[m] = t;
        }
#pragma unroll
        for (int n = 0; n < 4; ++n)
            b[n] = *(const bf16x8*)&Bs[(wc * 64 + n * 16 + frow) * BK + koff];
#pragma unroll
        for (int m = 0; m < 4; ++m)
#pragma unroll
            for (int n = 0; n < 4; ++n)
                acc[m][n] = __builtin_amdgcn_mfma_f32_16x16x32_bf16(
                    a[m], b[n], acc[m][n], 0, 0, 0);
        __syncthreads();
    }

    const int orow0 = brow + wr * 64 + (lane >> 4) * 4;
    const int ocol0 = bcol + wc * 64 + (lane & 15);
#pragma unroll
    for (int m = 0; m < 4; ++m)
#pragma unroll
        for (int n = 0; n < 4; ++n)
#pragma unroll
            for (int r = 0; r < 4; ++r)
                out[(size_t)(orow0 + m * 16 + r) * N + (ocol0 + n * 16)]
                    = acc[m][n][r];
}

extern "C" void kernel_launch(void* const* d_in, const int* in_sizes, int n_in,
                              void* d_out, int out_size, void* d_ws, size_t ws_size,
                              hipStream_t stream) {
    const float*          x      = (const float*)d_in[0];
    const unsigned short* wbits  = (const unsigned short*)d_in[1];  // fp32-delivered (r9)
    const int*            coords = (const int*)d_in[2];             // int32
    float*                out    = (float*)d_out;                   // fp32

    const size_t MB = 1024 * 1024;
    // W fp32 (16 MiB) parked in out rows [6144,8192); dead after wb convert,
    // so the GEMM's full-out writes are hazard-free.  wb bf16 (8 MiB) at ws+0
    // (r9-proven).  xb bf16 (32 MiB) at ws+8MiB when ws allows.
    float*          W  = out + W_BASE;
    unsigned short* wb = (unsigned short*)d_ws;
    unsigned short* xb = (unsigned short*)((char*)d_ws + 8 * MB);
    const bool full = ws_size >= 40 * MB;

    zero_f32_kernel<<<512, 256, 0, stream>>>((float4*)W, OUT_F * IN_F / 4);
    scatter_w_kernel<<<NNZ_ / 256, 256, 0, stream>>>(wbits, coords, W, NNZ_);
    f32_to_bf16_kernel<<<1024, 256, 0, stream>>>(
        (const float4*)W, (ushort4*)wb, OUT_F * IN_F / 4);

    dim3 grid(OUT_F / 128, BATCH / 128);   // 16 x 64 = 1024 blocks
    if (full) {
        f32_to_bf16_kernel<<<2048, 256, 0, stream>>>(
            (const float4*)x, (ushort4*)xb, BATCH * IN_F / 4);
        gemm_bf16_kernel<<<grid, 256, 0, stream>>>(xb, wb, out);
    } else {
        gemm_a32_kernel<<<grid, 256, 0, stream>>>(x, wb, out);
    }
}

// Round 11
// 165.432 us; speedup vs baseline: 6.8030x; 1.1825x over previous
//
#include <hip/hip_runtime.h>
#include <hip/hip_fp16.h>

#define IN_F   2048
#define OUT_F  2048
#define NNZ_   1048576
#define BATCH  8192
#define W_ROW0 6144
#define W_BASE ((size_t)W_ROW0 * OUT_F)   // W fp32 parked at out rows [6144,8192)

typedef __bf16 bf16x8 __attribute__((ext_vector_type(8)));
typedef float  f32x4  __attribute__((ext_vector_type(4)));

__device__ __forceinline__ float bfval(unsigned short b) {
    union { unsigned int u; float f; } t; t.u = ((unsigned int)b) << 16; return t.f;
}
__device__ __forceinline__ unsigned short f2bf(float f) {
    union { float f; unsigned int u; } v; v.f = f;
    unsigned int u = v.u; u += 0x7FFF + ((u >> 16) & 1);   // RNE
    return (unsigned short)(u >> 16);
}
__device__ __forceinline__ float h2f(unsigned short b) {
    union { unsigned short u; __half h; } t; t.u = b; return __half2float(t.h);
}
__device__ __forceinline__ void gload_lds16(const void* g, void* l) {
    __builtin_amdgcn_global_load_lds(
        (const __attribute__((address_space(1))) unsigned int*)g,
        (__attribute__((address_space(3))) unsigned int*)l,
        16, 0, 0);
}

// ---- prep: zero W fp32 region AND convert x fp32 -> bf16 (one launch) ----
__global__ void prep_kernel(const float4* __restrict__ x,
                            ushort4* __restrict__ xb,
                            float4* __restrict__ Wz) {
    const int stride = gridDim.x * blockDim.x;
    const int t0 = blockIdx.x * blockDim.x + threadIdx.x;
    for (int i = t0; i < OUT_F * IN_F / 4; i += stride)
        Wz[i] = float4{0.f, 0.f, 0.f, 0.f};
    for (int i = t0; i < BATCH * IN_F / 4; i += stride) {
        float4 v = x[i];
        ushort4 o;
        o.x = f2bf(v.x); o.y = f2bf(v.y); o.z = f2bf(v.z); o.w = f2bf(v.w);
        xb[i] = o;
    }
}

// ---- scatter COO -> dense W, 3-way dtype detection (r9-proven verbatim) ----
__global__ void scatter_w_kernel(const unsigned short* __restrict__ wbits,
                                 const int* __restrict__ coords,
                                 float* __restrict__ W, int nnz) {
    __shared__ unsigned int sbf, sfh;
    if (threadIdx.x == 0) { sbf = 0u; sfh = 0u; }
    __syncthreads();
    unsigned int mbf = 0u, mfh = 0u;
    for (int i = threadIdx.x; i < 512; i += blockDim.x) {
        unsigned short b = wbits[i];
        unsigned int abf = (((unsigned int)b) << 16) & 0x7FFFFFFFu;
        unsigned int afh = (unsigned int)(b & 0x7FFF);
        mbf = mbf > abf ? mbf : abf;
        mfh = mfh > afh ? mfh : afh;
    }
    atomicMax(&sbf, mbf); atomicMax(&sfh, mfh);
    __syncthreads();
    union { unsigned int u; float f; } tb; tb.u = sbf;
    float bmax = tb.f;
    float hmax = h2f((unsigned short)sfh);
    int mode = (bmax > 1e-3f && bmax < 16.f) ? 0
             : (hmax > 1e-3f && hmax < 16.f) ? 1 : 2;   // resolved on HW: 2 (fp32)

    int i = blockIdx.x * blockDim.x + threadIdx.x;
    if (i < nnz) {
        float v;
        if (mode == 0)      v = bfval(wbits[i]);
        else if (mode == 1) v = h2f(wbits[i]);
        else                v = ((const float*)wbits)[i];
        atomicAdd(&W[coords[i] & (OUT_F * IN_F - 1)], v);
    }
}

// ---- W fp32 -> wb bf16 ----
__global__ void f32_to_bf16_kernel(const float4* __restrict__ in,
                                   ushort4* __restrict__ out, int n4) {
    int s = gridDim.x * blockDim.x;
    for (int i = blockIdx.x * blockDim.x + threadIdx.x; i < n4; i += s) {
        float4 v = in[i];
        ushort4 o;
        o.x = f2bf(v.x); o.y = f2bf(v.y); o.z = f2bf(v.z); o.w = f2bf(v.w);
        out[i] = o;
    }
}

// ---- 256x256 bf16 GEMM, counted-vmcnt pipeline, XOR-swizzled LDS ----
// out[8192][2048](fp32) = xb[8192][2048] * wb[2048][2048]^T
// 8 waves (2Mx4N), per-wave 128x64 C, BK=64, LDS 128 KiB double-buffered.
__global__ __launch_bounds__(512, 1) void gemm256_kernel(
    const unsigned short* __restrict__ xb,
    const unsigned short* __restrict__ wb,
    float* __restrict__ out) {
    constexpr int K = IN_F;
    constexpr int NT = K / 64;                 // 32 K-tiles

    __shared__ __align__(16) unsigned short As[2][256 * 64];   // 64 KiB
    __shared__ __align__(16) unsigned short Bs[2][256 * 64];   // 64 KiB

    const int tid  = threadIdx.x;
    const int lane = tid & 63;
    const int wave = tid >> 6;        // 0..7
    const int wr   = wave >> 2;       // 0..1  (M half)
    const int wc   = wave & 3;        // 0..3  (N quarter)
    const int frow = lane & 15;
    const int klan = lane >> 4;       // 0..3
    const int s0   = klan ^ (lane & 7);         // read slot, ks=0 (ks=1: ^4)

    // XCD swizzle: 32-block chunks share one B panel (tn) per XCD L2
    const int flat = blockIdx.x;                 // 0..255
    const int swz  = (flat & 7) * 32 + (flat >> 3);
    const int tm   = swz & 31;                   // M tile 0..31
    const int tn   = swz >> 5;                   // N tile 0..7

    const unsigned short* srcA = xb + (size_t)tm * 256 * K;
    const unsigned short* srcB = wb + (size_t)tn * 256 * K;

    // staging lane constants: lane covers row rloc of its 8-row stripe,
    // source col-slot pre-swizzled so linear DMA + swizzled read agree
    const int rloc  = lane >> 3;                 // 0..7
    const int sslot = (lane & 7) ^ rloc;         // source 16B-slot

    f32x4 acc[8][4] = {};

    auto stage = [&](int buf, int kt) {
        const size_t coff = (size_t)kt * 64 + sslot * 8;
#pragma unroll
        for (int i = 0; i < 4; ++i) {
            const int row = i * 64 + wave * 8;   // wave-uniform
            gload_lds16(srcA + (size_t)(row + rloc) * K + coff,
                        &As[buf][row * 64]);
        }
#pragma unroll
        for (int i = 0; i < 4; ++i) {
            const int row = i * 64 + wave * 8;
            gload_lds16(srcB + (size_t)(row + rloc) * K + coff,
                        &Bs[buf][row * 64]);
        }
    };

    auto compute = [&](int buf) {
#pragma unroll
        for (int ks = 0; ks < 2; ++ks) {
            const int sl = s0 ^ (ks * 4);
            bf16x8 af[8], bg[4];
#pragma unroll
            for (int mf = 0; mf < 8; ++mf)
                af[mf] = *(const bf16x8*)
                    &As[buf][(wr * 128 + mf * 16 + frow) * 64 + sl * 8];
#pragma unroll
            for (int nf = 0; nf < 4; ++nf)
                bg[nf] = *(const bf16x8*)
                    &Bs[buf][(wc * 64 + nf * 16 + frow) * 64 + sl * 8];
            __builtin_amdgcn_s_setprio(1);
#pragma unroll
            for (int mf = 0; mf < 8; ++mf)
#pragma unroll
                for (int nf = 0; nf < 4; ++nf)
                    acc[mf][nf] = __builtin_amdgcn_mfma_f32_16x16x32_bf16(
                        af[mf], bg[nf], acc[mf][nf], 0, 0, 0);
            __builtin_amdgcn_s_setprio(0);
        }
    };

    // prologue: 2 K-tiles in flight (16 loads)
    stage(0, 0);
    stage(1, 1);

    for (int kt = 0; kt < NT - 2; ++kt) {
        asm volatile("s_waitcnt vmcnt(8)" ::: "memory");  // kt's 8 loads landed
        __builtin_amdgcn_s_barrier();
        compute(kt & 1);
        asm volatile("" ::: "memory");
        __builtin_amdgcn_s_barrier();                     // all waves done reading buf
        stage(kt & 1, kt + 2);                            // refill; stays in flight
    }
    // kt = NT-2 (no more staging)
    asm volatile("s_waitcnt vmcnt(8)" ::: "memory");
    __builtin_amdgcn_s_barrier();
    compute((NT - 2) & 1);
    asm volatile("" ::: "memory");
    __builtin_amdgcn_s_barrier();
    // kt = NT-1 (drain)
    asm volatile("s_waitcnt vmcnt(0)" ::: "memory");
    __builtin_amdgcn_s_barrier();
    compute((NT - 1) & 1);

    // epilogue: C/D layout col=lane&15, row=(lane>>4)*4+reg  [r3/r10-validated]
    const int orow0 = tm * 256 + wr * 128 + klan * 4;
    const int ocol0 = tn * 256 + wc * 64 + frow;
#pragma unroll
    for (int mf = 0; mf < 8; ++mf)
#pragma unroll
        for (int nf = 0; nf < 4; ++nf)
#pragma unroll
            for (int r = 0; r < 4; ++r)
                out[(size_t)(orow0 + mf * 16 + r) * OUT_F + ocol0 + nf * 16]
                    = acc[mf][nf][r];
}

extern "C" void kernel_launch(void* const* d_in, const int* in_sizes, int n_in,
                              void* d_out, int out_size, void* d_ws, size_t ws_size,
                              hipStream_t stream) {
    const float*          x      = (const float*)d_in[0];
    const unsigned short* wbits  = (const unsigned short*)d_in[1];  // fp32-delivered
    const int*            coords = (const int*)d_in[2];             // int32
    float*                out    = (float*)d_out;                   // fp32

    const size_t MB = 1024 * 1024;
    // W fp32 (16 MiB) in out rows [6144,8192) (dead after wb convert; GEMM
    // overwrites). wb bf16 (8 MiB) at ws+0, xb bf16 (32 MiB) at ws+8MiB
    // (ws >= 40 MiB proven by r10's full-path pass).
    float*          W  = out + W_BASE;
    unsigned short* wb = (unsigned short*)d_ws;
    unsigned short* xb = (unsigned short*)((char*)d_ws + 8 * MB);
    (void)ws_size; (void)in_sizes; (void)n_in; (void)out_size;

    prep_kernel<<<2048, 256, 0, stream>>>((const float4*)x, (ushort4*)xb,
                                          (float4*)W);
    scatter_w_kernel<<<NNZ_ / 256, 256, 0, stream>>>(wbits, coords, W, NNZ_);
    f32_to_bf16_kernel<<<1024, 256, 0, stream>>>(
        (const float4*)W, (ushort4*)wb, OUT_F * IN_F / 4);

    gemm256_kernel<<<256, 512, 0, stream>>>(xb, wb, out);
}